// Round 1
// baseline (335.890 us; speedup 1.0000x reference)
//
#include <hip/hip_runtime.h>
#include <hip/hip_bf16.h>

// L0 contraction: B rows x 15 fp32 features -> B rows x 3 fp32 outputs.
// out[b][s] = cg_s * sum_{j in seg s} sphc[b][j]^2, segments widths {3,5,7},
// cg values at flat indices {0,3,8} of cg_rep.
//
// Memory-bound: 240 MB in + 48 MB out = 288 MB -> ~46 us floor at 6.3 TB/s.
// Row stride = 60 B (not 16B-aligned), so we stage a 256-row tile (3840
// floats = 960 float4, 16B-aligned since 256*15*4 % 16 == 0) through LDS
// with fully coalesced float4 global loads, reduce per-row from LDS
// (stride-15 = odd -> max 2-way bank aliasing, free on gfx950), and stage
// the 768-float output tile in LDS to write 192 coalesced float4.

constexpr int M = 15;            // features per row
constexpr int NSEG = 3;          // output segments
constexpr int RPB = 256;         // rows per block == block size
constexpr int IN_F4 = RPB * M / 4;     // 960 float4 per input tile
constexpr int OUT_F4 = RPB * NSEG / 4; // 192 float4 per output tile

__global__ __launch_bounds__(RPB)
void l0_contract_kernel(const float* __restrict__ sphc,
                        const float* __restrict__ cg_rep,
                        float* __restrict__ out,
                        int B) {
    __shared__ float s_in[RPB * M];     // 15360 B
    __shared__ float s_out[RPB * NSEG]; //  3072 B

    const int tid = threadIdx.x;
    const long long rowStart = (long long)blockIdx.x * RPB;
    const long long rowsLeft = (long long)B - rowStart;
    const int rowsHere = rowsLeft >= RPB ? RPB : (int)rowsLeft;

    // ---- global -> LDS staging (coalesced float4 in the common case) ----
    if (rowsHere == RPB) {
        const float4* __restrict__ g4 =
            (const float4*)(sphc + rowStart * M);
        float4* l4 = (float4*)s_in;
#pragma unroll
        for (int i = tid; i < IN_F4; i += RPB) {
            l4[i] = g4[i];
        }
    } else {
        const int n = rowsHere * M;
        const float* g = sphc + rowStart * M;
        for (int i = tid; i < n; i += RPB) s_in[i] = g[i];
    }
    __syncthreads();

    // cg constants (wave-uniform scalar loads, L1/L2-cached)
    const float c1 = cg_rep[0];  // l=1 block (3 elems)
    const float c2 = cg_rep[3];  // l=2 block (5 elems)
    const float c3 = cg_rep[8];  // l=3 block (7 elems)

    // ---- per-row reduction from LDS ----
    if (tid < rowsHere) {
        const float* r = s_in + tid * M;
        float a = r[0] * r[0] + r[1] * r[1] + r[2] * r[2];
        float b = r[3] * r[3] + r[4] * r[4] + r[5] * r[5]
                + r[6] * r[6] + r[7] * r[7];
        float c = r[8] * r[8] + r[9] * r[9] + r[10] * r[10]
                + r[11] * r[11] + r[12] * r[12] + r[13] * r[13]
                + r[14] * r[14];
        s_out[tid * NSEG + 0] = a * c1;
        s_out[tid * NSEG + 1] = b * c2;
        s_out[tid * NSEG + 2] = c * c3;
    }
    __syncthreads();

    // ---- LDS -> global output (coalesced float4 in the common case) ----
    if (rowsHere == RPB) {
        const float4* lo4 = (const float4*)s_out;
        float4* o4 = (float4*)(out + rowStart * NSEG);
        if (tid < OUT_F4) o4[tid] = lo4[tid];
    } else {
        const int n = rowsHere * NSEG;
        float* o = out + rowStart * NSEG;
        for (int i = tid; i < n; i += RPB) o[i] = s_out[i];
    }
}

extern "C" void kernel_launch(void* const* d_in, const int* in_sizes, int n_in,
                              void* d_out, int out_size, void* d_ws, size_t ws_size,
                              hipStream_t stream) {
    const float* sphc   = (const float*)d_in[0];
    const float* cg_rep = (const float*)d_in[1];
    // d_in[2] = segment_ids (int32) — segmentation is compile-time known
    float* out = (float*)d_out;

    const int B = in_sizes[0] / M;  // 4,000,000
    const int grid = (B + RPB - 1) / RPB;

    l0_contract_kernel<<<grid, RPB, 0, stream>>>(sphc, cg_rep, out, B);
}